// Round 4
// baseline (1500.946 us; speedup 1.0000x reference)
//
#include <hip/hip_runtime.h>

#define BB 4
#define CH 64
#define HH 96
#define WW 96
#define DD 8
#define NS 243   // (2D+1)*(2S+1)^2 = 3*9*9
#define CC 2     // c-chunk staged in LDS
#define CSTRIDE (HH * WW * DD)   // 73728 floats per channel

// ---------------------------------------------------------------------------
// Kernel 1: per-pixel masks. mask = clip(sum_d alpha, 0, 1), shape (B,H,W)
// ---------------------------------------------------------------------------
__global__ void masks_kernel(const float* __restrict__ a1,
                             const float* __restrict__ a2,
                             float* __restrict__ m1,
                             float* __restrict__ m2) {
    int p = blockIdx.x * 256 + threadIdx.x;
    if (p >= BB * HH * WW) return;
    float4 x0 = ((const float4*)a1)[p * 2];
    float4 x1 = ((const float4*)a1)[p * 2 + 1];
    float4 y0 = ((const float4*)a2)[p * 2];
    float4 y1 = ((const float4*)a2)[p * 2 + 1];
    float s1 = ((x0.x + x0.y) + (x0.z + x0.w)) + ((x1.x + x1.y) + (x1.z + x1.w));
    float s2 = ((y0.x + y0.y) + (y0.z + y0.w)) + ((y1.x + y1.y) + (y1.z + y1.w));
    m1[p] = fminf(fmaxf(s1, 0.0f), 1.0f);
    m2[p] = fminf(fmaxf(s2, 0.0f), 1.0f);
}

// ---------------------------------------------------------------------------
// Kernel 2: cost volume + FUSED mask volume. k-split (acc[9][4]=36 regs).
//
// vs round 3 (which was LDS-pipe saturated at ~306us, model 311us):
//  * f1 never touches LDS. Each thread's f1 values (x=xb*4..+3 at its own z)
//    had zero cross-thread reuse -- the LDS round trip was a pure transpose.
//    Now 4 strided global dwords per c (8 lanes/32B segments, L2-served:
//    the 27 (k,i)-siblings of a row share an XCD via the L%216 grid map).
//  * f2 staged by (z,x4): one ds_write_b128 per thread per c instead of
//    4 ds_write_b32. Per-thread LDS: 192 b128 reads + 64 b128 writes
//    = 3072 cyc/wave vs 6144 -> LDS floor ~155us.
//  * mask volume computed in the epilogue (m1/m2 rows are L1/L2-resident;
//    value = zz-in-range ? m1*m2 : m1, pads=1, operands pre-clipped) and
//    stored as a second coalesced float4 -> maskvol_kernel deleted, its
//    287 MB of stores now hide under the LDS-bound main loop.
// ---------------------------------------------------------------------------
__global__ __launch_bounds__(192, 3)
void cost_kernel(const float* __restrict__ f1,
                 const float* __restrict__ f2,
                 const float* __restrict__ m1,
                 const float* __restrict__ m2,
                 float* __restrict__ outc,
                 float* __restrict__ outm) {
    const int L = blockIdx.x;             // 0..10367
    const int u = L % 216;
    const int t9 = u >> 3;                // 0..26
    const int i = t9 % 9;                 // 0..8
    const int k = t9 / 9;                 // 0..2
    const int g = (L / 216) * 8 + (u & 7);// 0..383 = b*HH + y
    const int b = g / HH;
    const int y = g % HH;
    const int tid = threadIdx.x;
    const int xb = tid >> 3;              // compute: x-block 0..23
    const int z  = tid & 7;               // compute: z 0..7
    const int yp = y + i - 4;

    const int ex  = tid >> 1;             // epilogue/store pixel 0..95
    const int ezb = (tid & 1) * 4;        // epilogue z-base (0 or 4)
    const float m1v = m1[(b * HH + y) * WW + ex];

    // ---- fast path: source row fully y-padded -> cost 0, mask m1 (pad=1) ----
    if (yp < 0 || yp >= HH) {
        float4 mv = make_float4(m1v, m1v, m1v, m1v);
        #pragma unroll
        for (int j = 0; j < 9; ++j) {
            int s = k * 81 + i * 9 + j;
            size_t ro = ((size_t)(b * NS + s) * HH + y) * 192;
            ((float4*)outc)[ro + tid] = make_float4(0.f, 0.f, 0.f, 0.f);
            ((float4*)outm)[ro + tid] = mv;
        }
        return;
    }

    // f2s = [CC][10 planes][104], planes 0/9 are z-halos, dwords {0..3,100..103}
    // x-halos (all zero). Epilogue reuses smem as 3x768 transpose scratch.
    __shared__ __align__(16) float smem[2304];
    float* f2s = smem;

    for (int n = tid; n < CC * 1040; n += 192) f2s[n] = 0.0f;

    const int sx = tid % 24;        // staging x4-group 0..23
    const int sz = tid / 24;        // staging z 0..7

    const float* f1g = f1 + ((size_t)(b * CH) * HH + y ) * (WW * DD);
    const float* f2g = f2 + ((size_t)(b * CH) * HH + yp) * (WW * DD);
    const int f2off = (sx * 4) * 8 + sz;       // + t*8 per element
    const int f1off = (xb * 4) * 8 + z;
    const int sdst  = (sz + 1) * 104 + sx * 4 + 4;   // 16B-aligned dword

    float pf[CC][4];
    #pragma unroll
    for (int c = 0; c < CC; ++c)
        #pragma unroll
        for (int t = 0; t < 4; ++t)
            pf[c][t] = f2g[(size_t)c * CSTRIDE + f2off + t * 8];

    float acc[9][4];
    #pragma unroll
    for (int j = 0; j < 9; ++j)
        #pragma unroll
        for (int t = 0; t < 4; ++t)
            acc[j][t] = 0.0f;

    for (int c0 = 0; c0 < CH; c0 += CC) {
        __syncthreads();            // previous chunk's LDS reads complete
        #pragma unroll
        for (int c = 0; c < CC; ++c) {
            float4 v;
            v.x = pf[c][0]; v.y = pf[c][1]; v.z = pf[c][2]; v.w = pf[c][3];
            *(float4*)&f2s[c * 1040 + sdst] = v;
        }
        __syncthreads();
        // prefetch AFTER the barrier (its vmcnt(0) would drain these)
        if (c0 + CC < CH) {
            #pragma unroll
            for (int c = 0; c < CC; ++c)
                #pragma unroll
                for (int t = 0; t < 4; ++t)
                    pf[c][t] = f2g[(size_t)(c0 + CC + c) * CSTRIDE + f2off + t * 8];
        }

        #pragma unroll
        for (int c = 0; c < CC; ++c) {
            float f1a[4];
            #pragma unroll
            for (int t = 0; t < 4; ++t)
                f1a[t] = f1g[(size_t)(c0 + c) * CSTRIDE + f1off + t * 8];
            const float* wp = &f2s[c * 1040 + (z + k) * 104 + xb * 4];
            float4 w0 = *(const float4*)(wp);
            float4 w1 = *(const float4*)(wp + 4);
            float4 w2 = *(const float4*)(wp + 8);
            float w[12] = {w0.x, w0.y, w0.z, w0.w,
                           w1.x, w1.y, w1.z, w1.w,
                           w2.x, w2.y, w2.z, w2.w};
            #pragma unroll
            for (int t = 0; t < 4; ++t)
                #pragma unroll
                for (int j = 0; j < 9; ++j)
                    acc[j][t] = fmaf(f1a[t], w[t + j], acc[j][t]);
        }
    }

    // ---- epilogue: swizzled transpose + cost store + fused mask store ----
    __syncthreads();                // all compute reads of smem done
    float* sbuf = smem;             // 3*768 = 2304 floats
    int wsw[4];
    #pragma unroll
    for (int t = 0; t < 4; ++t) {
        int d  = (xb * 4 + t) * 8 + z;     // dword index 0..767 (x*8+z)
        int bb = d >> 2;                   // 16B block 0..191
        int sb = bb ^ ((bb >> 3) & 7);     // XOR swizzle (involution)
        wsw[t] = (sb << 2) | (d & 3);
    }
    const int rsw = (tid ^ ((tid >> 3) & 7)) << 2;

    const float* m2b = m2 + (b * HH + yp) * WW;

    #pragma unroll
    for (int jb = 0; jb < 3; ++jb) {
        #pragma unroll
        for (int jj = 0; jj < 3; ++jj)
            #pragma unroll
            for (int t = 0; t < 4; ++t)
                sbuf[jj * 768 + wsw[t]] = acc[jb * 3 + jj][t] * 0.015625f;
        __syncthreads();
        #pragma unroll
        for (int jj = 0; jj < 3; ++jj) {
            int j = jb * 3 + jj;
            int s = k * 81 + i * 9 + j;
            size_t ro = ((size_t)(b * NS + s) * HH + y) * 192;
            float4 v = *(float4*)&sbuf[jj * 768 + rsw];
            ((float4*)outc)[ro + tid] = v;
            // mask: pad=1 everywhere OOR; m1,m2 pre-clipped so product needs no clip
            int xp = ex + j - 4;
            float m2v = ((unsigned)xp < WW) ? m2b[xp] : 1.0f;
            float pv = m1v * m2v;
            float4 mv;
            float* mp = (float*)&mv;
            #pragma unroll
            for (int q = 0; q < 4; ++q) {
                int zz = ezb + q + k - 1;
                mp[q] = ((unsigned)zz < DD) ? pv : m1v;
            }
            ((float4*)outm)[ro + tid] = mv;
        }
        __syncthreads();            // before next batch overwrites sbuf
    }
}

// ---------------------------------------------------------------------------
extern "C" void kernel_launch(void* const* d_in, const int* in_sizes, int n_in,
                              void* d_out, int out_size, void* d_ws, size_t ws_size,
                              hipStream_t stream) {
    const float* f1 = (const float*)d_in[0];  // mpi1_features (4,64,96,96,8)
    const float* a1 = (const float*)d_in[1];  // mpi1_alpha    (4,1,96,96,8)
    const float* f2 = (const float*)d_in[2];  // mpi2_features
    const float* a2 = (const float*)d_in[3];  // mpi2_alpha

    float* out      = (float*)d_out;
    float* out_cost = out;                                   // (B,NS,H,W,D)
    float* out_mask = out + (size_t)BB * NS * HH * WW * DD;  // second output

    float* m1 = (float*)d_ws;                 // B*H*W floats
    float* m2 = m1 + BB * HH * WW;            // B*H*W floats (295 KB total)

    masks_kernel<<<(BB * HH * WW + 255) / 256, 256, 0, stream>>>(a1, a2, m1, m2);
    cost_kernel<<<10368, 192, 0, stream>>>(f1, f2, m1, m2, out_cost, out_mask);
}

// Round 5
// 1342.581 us; speedup vs baseline: 1.1180x; 1.1180x over previous
//
#include <hip/hip_runtime.h>

#define BB 4
#define CH 64
#define HH 96
#define WW 96
#define DD 8
#define NS 243   // (2D+1)*(2S+1)^2 = 3*9*9
#define CC 2     // c-chunk staged in LDS

// ---------------------------------------------------------------------------
// Kernel 1: per-pixel masks. mask = clip(sum_d alpha, 0, 1), shape (B,H,W)
// ---------------------------------------------------------------------------
__global__ void masks_kernel(const float* __restrict__ a1,
                             const float* __restrict__ a2,
                             float* __restrict__ m1,
                             float* __restrict__ m2) {
    int p = blockIdx.x * 256 + threadIdx.x;
    if (p >= BB * HH * WW) return;
    float4 x0 = ((const float4*)a1)[p * 2];
    float4 x1 = ((const float4*)a1)[p * 2 + 1];
    float4 y0 = ((const float4*)a2)[p * 2];
    float4 y1 = ((const float4*)a2)[p * 2 + 1];
    float s1 = ((x0.x + x0.y) + (x0.z + x0.w)) + ((x1.x + x1.y) + (x1.z + x1.w));
    float s2 = ((y0.x + y0.y) + (y0.z + y0.w)) + ((y1.x + y1.y) + (y1.z + y1.w));
    m1[p] = fminf(fmaxf(s1, 0.0f), 1.0f);
    m2[p] = fminf(fmaxf(s2, 0.0f), 1.0f);
}

// ---------------------------------------------------------------------------
// Kernel 2: cost volume + fused mask volume, k-MERGED.
//
// Round-3 (k-split) was LDS-pipe saturated (model 304us = measured 306):
// the 3 k-sibling blocks at each (i,y,b) staged IDENTICAL f1/f2 rows, so
// 2/3 of all staging (and f1 reads) was redundant. Merging k back:
// LDS cyc per FMA drops 2.67 -> 1.56 (per c per wave: 8 b32 writes + 10
// b128 reads = 168 cyc for 108 FMAs). Floor ~200us vs R3's 304.
// Round-0 (also k-merged) ran at 2 blocks/CU because 29KB LDS hit the
// 64KB pool; CC=2 gives 14.5KB -> 4 blocks/CU, and the prefetch is issued
// AFTER the staging barrier (R3's fix: the barrier's vmcnt(0) otherwise
// drains it every chunk).
// Round-4 lesson baked in: every global load is a lane-contiguous float4
// (strided dword gathers were a 3x regression, VMEM-issue bound).
// Mask volume fused into the epilogue (R4, verified): value =
// zz-in-range ? m1*m2 : m1, pads = 1, operands pre-clipped.
// ---------------------------------------------------------------------------
__global__ __launch_bounds__(192, 3)
void cost_kernel(const float* __restrict__ f1,
                 const float* __restrict__ f2,
                 const float* __restrict__ m1,
                 const float* __restrict__ m2,
                 float* __restrict__ outc,
                 float* __restrict__ outm) {
    const int L = blockIdx.x;             // 0..3455
    const int u = L % 72;
    const int i = u >> 3;                 // 0..8
    const int g = (L / 72) * 8 + (u & 7); // 0..383 = b*HH + y
    const int b = g / HH;
    const int y = g % HH;
    const int tid = threadIdx.x;
    const int xb = tid >> 3;              // compute: x-block 0..23
    const int z  = tid & 7;               // compute: z 0..7
    const int yp = y + i - 4;

    const int ex  = tid >> 1;             // store/mask pixel 0..95
    const int ezb = (tid & 1) * 4;        // store z-base (0 or 4)
    const float m1v = m1[(b * HH + y) * WW + ex];

    // ---- fast path: source row fully y-padded -> cost 0, mask = m1 ----
    if (yp < 0 || yp >= HH) {
        float4 mv = make_float4(m1v, m1v, m1v, m1v);
        #pragma unroll
        for (int k = 0; k < 3; ++k)
            #pragma unroll
            for (int j = 0; j < 9; ++j) {
                int s = k * 81 + i * 9 + j;
                size_t ro = ((size_t)(b * NS + s) * HH + y) * 192;
                ((float4*)outc)[ro + tid] = make_float4(0.f, 0.f, 0.f, 0.f);
                ((float4*)outm)[ro + tid] = mv;
            }
        return;
    }

    // f1s [CC][8 z][96 x] = 1536 floats; f2s [CC][10 z-planes][104 x] = 2080
    // floats (planes 0/9 and x 0..3,100..103 are zero halos). 14464 B total.
    // Epilogue reuses smem as 3x768 transpose scratch.
    __shared__ __align__(16) float smem[CC * 768 + CC * 1040];
    float* f1s = smem;
    float* f2s = smem + CC * 768;

    for (int n = tid; n < CC * 1040; n += 192) f2s[n] = 0.0f;

    const int xs  = tid >> 1;       // staging pixel 0..95
    const int zb4 = (tid & 1) * 4;  // staging z-base (0 or 4)

    const float4* f1r = (const float4*)f1 + ((size_t)(b * CH) * HH + y ) * 192;
    const float4* f2r = (const float4*)f2 + ((size_t)(b * CH) * HH + yp) * 192;

    float4 p1[CC], p2[CC];
    #pragma unroll
    for (int c = 0; c < CC; ++c) {
        p1[c] = f1r[(size_t)c * (HH * 192) + tid];
        p2[c] = f2r[(size_t)c * (HH * 192) + tid];
    }

    float acc[3][9][4];
    #pragma unroll
    for (int k = 0; k < 3; ++k)
        #pragma unroll
        for (int j = 0; j < 9; ++j)
            #pragma unroll
            for (int t = 0; t < 4; ++t)
                acc[k][j][t] = 0.0f;

    for (int c0 = 0; c0 < CH; c0 += CC) {
        __syncthreads();            // previous chunk's LDS reads complete
        #pragma unroll
        for (int c = 0; c < CC; ++c) {
            f1s[c * 768 + (zb4 + 0) * 96 + xs] = p1[c].x;
            f1s[c * 768 + (zb4 + 1) * 96 + xs] = p1[c].y;
            f1s[c * 768 + (zb4 + 2) * 96 + xs] = p1[c].z;
            f1s[c * 768 + (zb4 + 3) * 96 + xs] = p1[c].w;
            f2s[c * 1040 + (zb4 + 1) * 104 + xs + 4] = p2[c].x;  // plane z+1
            f2s[c * 1040 + (zb4 + 2) * 104 + xs + 4] = p2[c].y;
            f2s[c * 1040 + (zb4 + 3) * 104 + xs + 4] = p2[c].z;
            f2s[c * 1040 + (zb4 + 4) * 104 + xs + 4] = p2[c].w;
        }
        __syncthreads();
        // prefetch AFTER the barrier (its vmcnt(0) would drain these)
        if (c0 + CC < CH) {
            #pragma unroll
            for (int c = 0; c < CC; ++c) {
                p1[c] = f1r[(size_t)(c0 + CC + c) * (HH * 192) + tid];
                p2[c] = f2r[(size_t)(c0 + CC + c) * (HH * 192) + tid];
            }
        }

        #pragma unroll
        for (int c = 0; c < CC; ++c) {
            float4 f1v = *(const float4*)&f1s[c * 768 + z * 96 + xb * 4];
            float f1a[4] = {f1v.x, f1v.y, f1v.z, f1v.w};
            #pragma unroll
            for (int k = 0; k < 3; ++k) {
                // compute needs f2 at z' = z+k-1 -> stored plane z'+1 = z+k
                const float* wp = &f2s[c * 1040 + (z + k) * 104 + xb * 4];
                float4 w0 = *(const float4*)(wp);
                float4 w1 = *(const float4*)(wp + 4);
                float4 w2 = *(const float4*)(wp + 8);
                float w[12] = {w0.x, w0.y, w0.z, w0.w,
                               w1.x, w1.y, w1.z, w1.w,
                               w2.x, w2.y, w2.z, w2.w};
                #pragma unroll
                for (int t = 0; t < 4; ++t)
                    #pragma unroll
                    for (int j = 0; j < 9; ++j)
                        acc[k][j][t] = fmaf(f1a[t], w[t + j], acc[k][j][t]);
            }
        }
    }

    // ---- epilogue: swizzled transpose + cost store + fused mask store ----
    __syncthreads();                // all compute reads of smem done
    float* sbuf = smem;             // 3*768 = 2304 floats <= 3616
    int wsw[4];
    #pragma unroll
    for (int t = 0; t < 4; ++t) {
        int d  = (xb * 4 + t) * 8 + z;     // dword index 0..767 (x*8+z)
        int bb = d >> 2;                   // 16B block 0..191
        int sb = bb ^ ((bb >> 3) & 7);     // XOR swizzle (involution)
        wsw[t] = (sb << 2) | (d & 3);
    }
    const int rsw = (tid ^ ((tid >> 3) & 7)) << 2;

    const float* m2b = m2 + (b * HH + yp) * WW;

    #pragma unroll
    for (int k = 0; k < 3; ++k)
        #pragma unroll
        for (int jb = 0; jb < 3; ++jb) {
            #pragma unroll
            for (int jj = 0; jj < 3; ++jj)
                #pragma unroll
                for (int t = 0; t < 4; ++t)
                    sbuf[jj * 768 + wsw[t]] = acc[k][jb * 3 + jj][t] * 0.015625f;
            __syncthreads();
            #pragma unroll
            for (int jj = 0; jj < 3; ++jj) {
                int j = jb * 3 + jj;
                int s = k * 81 + i * 9 + j;
                size_t ro = ((size_t)(b * NS + s) * HH + y) * 192;
                float4 v = *(float4*)&sbuf[jj * 768 + rsw];
                ((float4*)outc)[ro + tid] = v;
                // mask: pads = 1 (y handled by fast path); m1,m2 pre-clipped
                int xp = ex + j - 4;
                float m2v = ((unsigned)xp < WW) ? m2b[xp] : 1.0f;
                float pv = m1v * m2v;
                float4 mv;
                float* mp = (float*)&mv;
                #pragma unroll
                for (int q = 0; q < 4; ++q) {
                    int zz = ezb + q + k - 1;
                    mp[q] = ((unsigned)zz < DD) ? pv : m1v;
                }
                ((float4*)outm)[ro + tid] = mv;
            }
            __syncthreads();        // before next batch overwrites sbuf
        }
}

// ---------------------------------------------------------------------------
extern "C" void kernel_launch(void* const* d_in, const int* in_sizes, int n_in,
                              void* d_out, int out_size, void* d_ws, size_t ws_size,
                              hipStream_t stream) {
    const float* f1 = (const float*)d_in[0];  // mpi1_features (4,64,96,96,8)
    const float* a1 = (const float*)d_in[1];  // mpi1_alpha    (4,1,96,96,8)
    const float* f2 = (const float*)d_in[2];  // mpi2_features
    const float* a2 = (const float*)d_in[3];  // mpi2_alpha

    float* out      = (float*)d_out;
    float* out_cost = out;                                   // (B,NS,H,W,D)
    float* out_mask = out + (size_t)BB * NS * HH * WW * DD;  // second output

    float* m1 = (float*)d_ws;                 // B*H*W floats
    float* m2 = m1 + BB * HH * WW;            // B*H*W floats (295 KB total)

    masks_kernel<<<(BB * HH * WW + 255) / 256, 256, 0, stream>>>(a1, a2, m1, m2);
    cost_kernel<<<3456, 192, 0, stream>>>(f1, f2, m1, m2, out_cost, out_mask);
}

// Round 6
// 864.497 us; speedup vs baseline: 1.7362x; 1.5530x over previous
//
#include <hip/hip_runtime.h>

#define BB 4
#define CH 64
#define HH 96
#define WW 96
#define DD 8
#define NS 243   // (2D+1)*(2S+1)^2 = 3*9*9
#define CC 2     // c-chunk staged in LDS

// ---------------------------------------------------------------------------
// Kernel 1: per-pixel masks. mask = clip(sum_d alpha, 0, 1), shape (B,H,W)
// ---------------------------------------------------------------------------
__global__ void masks_kernel(const float* __restrict__ a1,
                             const float* __restrict__ a2,
                             float* __restrict__ m1,
                             float* __restrict__ m2) {
    int p = blockIdx.x * 256 + threadIdx.x;
    if (p >= BB * HH * WW) return;
    float4 x0 = ((const float4*)a1)[p * 2];
    float4 x1 = ((const float4*)a1)[p * 2 + 1];
    float4 y0 = ((const float4*)a2)[p * 2];
    float4 y1 = ((const float4*)a2)[p * 2 + 1];
    float s1 = ((x0.x + x0.y) + (x0.z + x0.w)) + ((x1.x + x1.y) + (x1.z + x1.w));
    float s2 = ((y0.x + y0.y) + (y0.z + y0.w)) + ((y1.x + y1.y) + (y1.z + y1.w));
    m1[p] = fminf(fmaxf(s1, 0.0f), 1.0f);
    m2[p] = fminf(fmaxf(s2, 0.0f), 1.0f);
}

// ---------------------------------------------------------------------------
// Kernel 2: cost volume + fused mask volume, k-MERGED, 128-VGPR budget.
//
// Measured design space (R0-R5):
//  * k-split (acc=36, 12 waves/CU): LDS-pipe saturated ~306us -- the 3
//    k-siblings restage identical rows; 2.67 LDS cyc/FMA is the floor.
//  * k-merged (acc=108): 1.56 LDS cyc/FMA, floor ~200us, but needs ~128
//    VGPR. R5's (192,3)=85-reg cap SPILLED acc (WRITE 574MB->2.1GB, 852us).
//    -> __launch_bounds__(192,2): 128-reg cap, proven to fit this acc shape
//    in R0. 2 blocks/CU is intentional: per-chunk LDS wall time (~2016 cyc
//    at 6 waves/CU) exceeds HBM latency (~900 cyc), so the after-barrier
//    prefetch (R3 fix: issued BEFORE the barrier it would be drained by its
//    vmcnt(0) every chunk) stays hidden even at low occupancy.
//  * All global loads lane-contiguous float4 (R4: strided dword gathers
//    were 3x worse, VMEM-issue bound).
//  * Mask volume fused into the epilogue (R4, verified correct): value =
//    zz-in-range ? m1*m2 : m1, pads = 1, operands pre-clipped.
// ---------------------------------------------------------------------------
__global__ __launch_bounds__(192, 2)
void cost_kernel(const float* __restrict__ f1,
                 const float* __restrict__ f2,
                 const float* __restrict__ m1,
                 const float* __restrict__ m2,
                 float* __restrict__ outc,
                 float* __restrict__ outm) {
    const int L = blockIdx.x;             // 0..3455
    const int u = L % 72;
    const int i = u >> 3;                 // 0..8
    const int g = (L / 72) * 8 + (u & 7); // 0..383 = b*HH + y
    const int b = g / HH;
    const int y = g % HH;
    const int tid = threadIdx.x;
    const int xb = tid >> 3;              // compute: x-block 0..23
    const int z  = tid & 7;               // compute: z 0..7
    const int yp = y + i - 4;

    const int ex  = tid >> 1;             // store/mask pixel 0..95
    const int ezb = (tid & 1) * 4;        // store z-base (0 or 4)
    const float m1v = m1[(b * HH + y) * WW + ex];

    // ---- fast path: source row fully y-padded -> cost 0, mask = m1 ----
    if (yp < 0 || yp >= HH) {
        float4 mv = make_float4(m1v, m1v, m1v, m1v);
        #pragma unroll
        for (int k = 0; k < 3; ++k)
            #pragma unroll
            for (int j = 0; j < 9; ++j) {
                int s = k * 81 + i * 9 + j;
                size_t ro = ((size_t)(b * NS + s) * HH + y) * 192;
                ((float4*)outc)[ro + tid] = make_float4(0.f, 0.f, 0.f, 0.f);
                ((float4*)outm)[ro + tid] = mv;
            }
        return;
    }

    // f1s [CC][8 z][96 x] = 1536 floats; f2s [CC][10 z-planes][104 x] = 2080
    // floats (planes 0/9 and x 0..3,100..103 are zero halos). 14464 B total.
    // Epilogue reuses smem as 3x768 transpose scratch.
    __shared__ __align__(16) float smem[CC * 768 + CC * 1040];
    float* f1s = smem;
    float* f2s = smem + CC * 768;

    for (int n = tid; n < CC * 1040; n += 192) f2s[n] = 0.0f;

    const int xs  = tid >> 1;       // staging pixel 0..95
    const int zb4 = (tid & 1) * 4;  // staging z-base (0 or 4)

    const float4* f1r = (const float4*)f1 + ((size_t)(b * CH) * HH + y ) * 192;
    const float4* f2r = (const float4*)f2 + ((size_t)(b * CH) * HH + yp) * 192;

    float4 p1[CC], p2[CC];
    #pragma unroll
    for (int c = 0; c < CC; ++c) {
        p1[c] = f1r[(size_t)c * (HH * 192) + tid];
        p2[c] = f2r[(size_t)c * (HH * 192) + tid];
    }

    float acc[3][9][4];
    #pragma unroll
    for (int k = 0; k < 3; ++k)
        #pragma unroll
        for (int j = 0; j < 9; ++j)
            #pragma unroll
            for (int t = 0; t < 4; ++t)
                acc[k][j][t] = 0.0f;

    for (int c0 = 0; c0 < CH; c0 += CC) {
        __syncthreads();            // previous chunk's LDS reads complete
        #pragma unroll
        for (int c = 0; c < CC; ++c) {
            f1s[c * 768 + (zb4 + 0) * 96 + xs] = p1[c].x;
            f1s[c * 768 + (zb4 + 1) * 96 + xs] = p1[c].y;
            f1s[c * 768 + (zb4 + 2) * 96 + xs] = p1[c].z;
            f1s[c * 768 + (zb4 + 3) * 96 + xs] = p1[c].w;
            f2s[c * 1040 + (zb4 + 1) * 104 + xs + 4] = p2[c].x;  // plane z+1
            f2s[c * 1040 + (zb4 + 2) * 104 + xs + 4] = p2[c].y;
            f2s[c * 1040 + (zb4 + 3) * 104 + xs + 4] = p2[c].z;
            f2s[c * 1040 + (zb4 + 4) * 104 + xs + 4] = p2[c].w;
        }
        __syncthreads();
        // prefetch AFTER the barrier (its vmcnt(0) would drain these)
        if (c0 + CC < CH) {
            #pragma unroll
            for (int c = 0; c < CC; ++c) {
                p1[c] = f1r[(size_t)(c0 + CC + c) * (HH * 192) + tid];
                p2[c] = f2r[(size_t)(c0 + CC + c) * (HH * 192) + tid];
            }
        }

        #pragma unroll
        for (int c = 0; c < CC; ++c) {
            float4 f1v = *(const float4*)&f1s[c * 768 + z * 96 + xb * 4];
            float f1a[4] = {f1v.x, f1v.y, f1v.z, f1v.w};
            #pragma unroll
            for (int k = 0; k < 3; ++k) {
                // compute needs f2 at z' = z+k-1 -> stored plane z'+1 = z+k
                const float* wp = &f2s[c * 1040 + (z + k) * 104 + xb * 4];
                float4 w0 = *(const float4*)(wp);
                float4 w1 = *(const float4*)(wp + 4);
                float4 w2 = *(const float4*)(wp + 8);
                float w[12] = {w0.x, w0.y, w0.z, w0.w,
                               w1.x, w1.y, w1.z, w1.w,
                               w2.x, w2.y, w2.z, w2.w};
                #pragma unroll
                for (int t = 0; t < 4; ++t)
                    #pragma unroll
                    for (int j = 0; j < 9; ++j)
                        acc[k][j][t] = fmaf(f1a[t], w[t + j], acc[k][j][t]);
            }
        }
    }

    // ---- epilogue: swizzled transpose + cost store + fused mask store ----
    __syncthreads();                // all compute reads of smem done
    float* sbuf = smem;             // 3*768 = 2304 floats <= 3616
    int wsw[4];
    #pragma unroll
    for (int t = 0; t < 4; ++t) {
        int d  = (xb * 4 + t) * 8 + z;     // dword index 0..767 (x*8+z)
        int bb = d >> 2;                   // 16B block 0..191
        int sb = bb ^ ((bb >> 3) & 7);     // XOR swizzle (involution)
        wsw[t] = (sb << 2) | (d & 3);
    }
    const int rsw = (tid ^ ((tid >> 3) & 7)) << 2;

    const float* m2b = m2 + (b * HH + yp) * WW;

    #pragma unroll
    for (int k = 0; k < 3; ++k)
        #pragma unroll
        for (int jb = 0; jb < 3; ++jb) {
            #pragma unroll
            for (int jj = 0; jj < 3; ++jj)
                #pragma unroll
                for (int t = 0; t < 4; ++t)
                    sbuf[jj * 768 + wsw[t]] = acc[k][jb * 3 + jj][t] * 0.015625f;
            __syncthreads();
            #pragma unroll
            for (int jj = 0; jj < 3; ++jj) {
                int j = jb * 3 + jj;
                int s = k * 81 + i * 9 + j;
                size_t ro = ((size_t)(b * NS + s) * HH + y) * 192;
                float4 v = *(float4*)&sbuf[jj * 768 + rsw];
                ((float4*)outc)[ro + tid] = v;
                // mask: pads = 1 (y handled by fast path); m1,m2 pre-clipped
                int xp = ex + j - 4;
                float m2v = ((unsigned)xp < WW) ? m2b[xp] : 1.0f;
                float pv = m1v * m2v;
                float4 mv;
                float* mp = (float*)&mv;
                #pragma unroll
                for (int q = 0; q < 4; ++q) {
                    int zz = ezb + q + k - 1;
                    mp[q] = ((unsigned)zz < DD) ? pv : m1v;
                }
                ((float4*)outm)[ro + tid] = mv;
            }
            __syncthreads();        // before next batch overwrites sbuf
        }
}

// ---------------------------------------------------------------------------
extern "C" void kernel_launch(void* const* d_in, const int* in_sizes, int n_in,
                              void* d_out, int out_size, void* d_ws, size_t ws_size,
                              hipStream_t stream) {
    const float* f1 = (const float*)d_in[0];  // mpi1_features (4,64,96,96,8)
    const float* a1 = (const float*)d_in[1];  // mpi1_alpha    (4,1,96,96,8)
    const float* f2 = (const float*)d_in[2];  // mpi2_features
    const float* a2 = (const float*)d_in[3];  // mpi2_alpha

    float* out      = (float*)d_out;
    float* out_cost = out;                                   // (B,NS,H,W,D)
    float* out_mask = out + (size_t)BB * NS * HH * WW * DD;  // second output

    float* m1 = (float*)d_ws;                 // B*H*W floats
    float* m2 = m1 + BB * HH * WW;            // B*H*W floats (295 KB total)

    masks_kernel<<<(BB * HH * WW + 255) / 256, 256, 0, stream>>>(a1, a2, m1, m2);
    cost_kernel<<<3456, 192, 0, stream>>>(f1, f2, m1, m2, out_cost, out_mask);
}